// Round 13
// baseline (4460.793 us; speedup 1.0000x reference)
//
#include <hip/hip_runtime.h>
#include <math.h>

#define BB 4
#define CC 64
#define NN 4096
#define OO 64
#define KNN 32

// ws layout (float offsets) — max footprint 23.66 MB (R0-proven)
#define XT_OFF    0u          // (B,N,C) fp32          1048576
#define SQ_OFF    1048576u    // (B,N) fp32             16384
#define P_OFF     1064960u    // (B,N,O)               1048576
#define BASE_OFF  2113536u    // (B,N,O)               1048576
#define HMAX_OFF  3162112u    // (B,N,O)               1048576
#define HMIN_OFF  4210688u    // (B,N,O)               1048576
#define STATS_OFF 5259264u    // 1024 x 128            131072
#define SCSH_OFF  5390336u    // 128
#define IDX_OFF   5390464u    // (B,N,K) int32         524288
// gap/i33 overlay the stats region (disjoint lifetimes: k2/k2f before k3)
#define GAP_OFF   5259264u    // (B*N) uint            16384
#define I33_OFF   5275648u    // (B*N) int             16384

__device__ __forceinline__ float keyToFloat(unsigned int u) {
  unsigned int b = (u & 0x80000000u) ? (u & 0x7fffffffu) : ~u;
  return __uint_as_float(b);
}

// ---------------- K1: transpose points (B,C,N)->(B,N,C) + fp32(sq64) ------
__global__ __launch_bounds__(256) void k1_transpose_sq(
    const float* __restrict__ pts, float* __restrict__ xT, float* __restrict__ sqf) {
  __shared__ float tile[64 * 65];
  __shared__ double sqp[256];
  const int t = threadIdx.x, blk = blockIdx.x;
  const int b = blk >> 6, n0 = (blk & 63) << 6;
  const float* pb = pts + (size_t)b * CC * NN;
  const int j = t & 63, cg = t >> 6;
  double acc = 0.0;
#pragma unroll
  for (int i = 0; i < 16; ++i) {
    int c = cg * 16 + i;
    float v = pb[(size_t)c * NN + n0 + j];
    tile[c * 65 + j] = v;
    acc += (double)v * (double)v;
  }
  sqp[t] = acc;
  __syncthreads();
  const int c2 = t & 63, jg = t >> 6;
#pragma unroll
  for (int i = 0; i < 16; ++i) {
    int jj = jg * 16 + i;
    xT[((size_t)b * NN + n0 + jj) * CC + c2] = tile[c2 * 65 + jj];
  }
  if (t < 64)
    sqf[b * NN + n0 + t] = (float)(sqp[t] + sqp[64 + t] + sqp[128 + t] + sqp[192 + t]);
}

// ---------------- K2b: P = x.w2^T, base = x.(w1-w2)^T ---------------------
__global__ __launch_bounds__(256) void k2b_small_gemm(
    const float* __restrict__ xT, const float* __restrict__ W,
    float* __restrict__ P, float* __restrict__ base) {
  __shared__ float w2T[64 * 65];
  __shared__ float wdT[64 * 65];
  __shared__ float xbuf[4 * 64];
  const int t = threadIdx.x, blk = blockIdx.x;
  const int b = blk >> 6, n0 = (blk & 63) << 6;
#pragma unroll
  for (int i = 0; i < 16; ++i) {
    int e = i * 256 + t, o = e >> 6, c = e & 63;
    w2T[c * 65 + o] = W[o * 128 + 64 + c];
  }
  __syncthreads();
#pragma unroll
  for (int i = 0; i < 16; ++i) {
    int e = i * 256 + t, o = e >> 6, c = e & 63;
    wdT[c * 65 + o] = W[o * 128 + c] - w2T[c * 65 + o];
  }
  __syncthreads();
  const int w = t >> 6, lane = t & 63;
  for (int it = 0; it < 16; ++it) {
    int n = n0 + it * 4 + w;
    xbuf[t] = xT[((size_t)b * NN + n) * CC + lane];
    __syncthreads();
    float accP = 0.f, accB = 0.f;
#pragma unroll
    for (int c = 0; c < 64; ++c) {
      float xc = xbuf[w * 64 + c];
      accP = fmaf(xc, w2T[c * 65 + lane], accP);
      accB = fmaf(xc, wdT[c * 65 + lane], accB);
    }
    size_t off = ((size_t)b * NN + n) * OO + lane;
    P[off] = accP;
    base[off] = accB;
    __syncthreads();
  }
}

// ---------------- K2: fp64 Gram (2 rows/thread) + register-key select -----
// 2 rows/block, 256 threads, 16 tiles x 256 cols. Thread t owns col t of
// each tile for BOTH rows; 32 keys live in VGPRs (straight-line tile steps).
// Select: R11's 32-round binary search (counts from registers, one barrier
// per round), then R12's proven membership/tie/finalize. Keys bit-identical.
__global__ __launch_bounds__(256, 2) void k2_gram_select(
    const float* __restrict__ xT, const float* __restrict__ sqf,
    int* __restrict__ idxout, unsigned int* __restrict__ gapb,
    int* __restrict__ i33out) {
  __shared__ __align__(16) float xmT[256 * 68];   // 69632 B
  __shared__ float sqm[256];
  __shared__ int rowcnt[2][2][4];                 // [parity][row][wave]
  __shared__ unsigned int sh_K33[2];
  __shared__ int sh_list[2][32];
  __shared__ int sh_eq[2][96];
  __shared__ unsigned int sh_kmin[2];
  __shared__ int sh_ngt[2], sh_i33[2], sh_mx[2], sh_cnt[2], sh_ecnt[2];

  const int t = threadIdx.x, blk = blockIdx.x;
  const int p0 = blk * 2;
  const int b = p0 >> 12;
  const int wid = t >> 6;
  const float* xb = xT + (size_t)b * NN * CC;

  float4 xr0[16], xr1[16];
  {
    const float4* r0p = (const float4*)(xT + (size_t)p0 * CC);
    const float4* r1p = (const float4*)(xT + (size_t)(p0 + 1) * CC);
#pragma unroll
    for (int cq = 0; cq < 16; ++cq) { xr0[cq] = r0p[cq]; xr1[cq] = r1p[cq]; }
  }
  const float srf0 = sqf[p0], srf1 = sqf[p0 + 1];

  unsigned int kys[32];

#define TILE_STEP(ti)                                                          \
  {                                                                            \
    const int m0 = (ti) << 8;                                                  \
    __syncthreads();                                                           \
    for (int q = 0; q < 16; ++q) {                                             \
      int e = q * 256 + t;                                                     \
      int c2 = e >> 4, cq = e & 15;                                            \
      float4 v = ((const float4*)&xb[(size_t)(m0 + c2) * CC])[cq];             \
      *(float4*)&xmT[c2 * 68 + 4 * cq] = v;                                    \
    }                                                                          \
    sqm[t] = sqf[b * NN + m0 + t];                                             \
    __syncthreads();                                                           \
    double a0 = 0.0, a1 = 0.0;                                                 \
    _Pragma("unroll")                                                          \
    for (int cq = 0; cq < 16; ++cq) {                                          \
      float4 mv = *(const float4*)&xmT[t * 68 + 4 * cq];                       \
      a0 += (double)xr0[cq].x * (double)mv.x + (double)xr0[cq].y * (double)mv.y + \
            (double)xr0[cq].z * (double)mv.z + (double)xr0[cq].w * (double)mv.w; \
      a1 += (double)xr1[cq].x * (double)mv.x + (double)xr1[cq].y * (double)mv.y + \
            (double)xr1[cq].z * (double)mv.z + (double)xr1[cq].w * (double)mv.w; \
    }                                                                          \
    float g0 = (float)a0, g1 = (float)a1;                                      \
    float d0 = 2.0f * g0 - srf0; d0 = d0 - sqm[t];                             \
    float d1 = 2.0f * g1 - srf1; d1 = d1 - sqm[t];                             \
    unsigned int b0 = __float_as_uint(d0);                                     \
    unsigned int b1 = __float_as_uint(d1);                                     \
    kys[2 * (ti)]     = (b0 & 0x80000000u) ? ~b0 : (b0 | 0x80000000u);         \
    kys[2 * (ti) + 1] = (b1 & 0x80000000u) ? ~b1 : (b1 | 0x80000000u);         \
  }

  TILE_STEP(0)  TILE_STEP(1)  TILE_STEP(2)  TILE_STEP(3)
  TILE_STEP(4)  TILE_STEP(5)  TILE_STEP(6)  TILE_STEP(7)
  TILE_STEP(8)  TILE_STEP(9)  TILE_STEP(10) TILE_STEP(11)
  TILE_STEP(12) TILE_STEP(13) TILE_STEP(14) TILE_STEP(15)
#undef TILE_STEP

  // ---- binary search (R11 algorithm, register keys, both rows) ----
  unsigned int Pv0 = 0, Pv1 = 0;
  int R0 = 33, R1 = 33;
  for (int bit = 31; bit >= 0; --bit) {
    const unsigned int tgt0 = (Pv0 >> bit) | 1u;
    const unsigned int tgt1 = (Pv1 >> bit) | 1u;
    int c0 = 0, c1 = 0;
#pragma unroll
    for (int q = 0; q < 16; ++q) {
      c0 += ((kys[2 * q] >> bit) == tgt0);
      c1 += ((kys[2 * q + 1] >> bit) == tgt1);
    }
#pragma unroll
    for (int off = 32; off > 0; off >>= 1) {
      c0 += __shfl_down(c0, off, 64);
      c1 += __shfl_down(c1, off, 64);
    }
    if ((t & 63) == 0) {
      rowcnt[bit & 1][0][wid] = c0;
      rowcnt[bit & 1][1][wid] = c1;
    }
    __syncthreads();
    int s0 = rowcnt[bit & 1][0][0] + rowcnt[bit & 1][0][1] +
             rowcnt[bit & 1][0][2] + rowcnt[bit & 1][0][3];
    int s1 = rowcnt[bit & 1][1][0] + rowcnt[bit & 1][1][1] +
             rowcnt[bit & 1][1][2] + rowcnt[bit & 1][1][3];
    if (s0 >= R0) Pv0 |= (1u << bit); else R0 -= s0;
    if (s1 >= R1) Pv1 |= (1u << bit); else R1 -= s1;
  }

  if (t < 2) {
    sh_K33[t] = (t == 0) ? Pv0 : Pv1;   // all threads agree on Pv0/Pv1
    sh_ngt[t] = 0; sh_kmin[t] = 0xffffffffu; sh_i33[t] = 0x7fffffff;
    sh_mx[t] = -1; sh_cnt[t] = 0; sh_ecnt[t] = 0;
  }
  __syncthreads();

  const unsigned int K0 = sh_K33[0], K1 = sh_K33[1];

  {  // pass 1: ngt / kmin / i33
    int ng0 = 0, ng1 = 0;
    unsigned int km0 = 0xffffffffu, km1 = 0xffffffffu;
#pragma unroll
    for (int q = 0; q < 16; ++q) {
      unsigned int k0 = kys[2 * q], k1 = kys[2 * q + 1];
      int gi = (q << 8) + t;
      if (k0 > K0) { ng0++; km0 = k0 < km0 ? k0 : km0; }
      if (k0 == K0) atomicMin(&sh_i33[0], gi);
      if (k1 > K1) { ng1++; km1 = k1 < km1 ? k1 : km1; }
      if (k1 == K1) atomicMin(&sh_i33[1], gi);
    }
    if (ng0) { atomicAdd(&sh_ngt[0], ng0); atomicMin(&sh_kmin[0], km0); }
    if (ng1) { atomicAdd(&sh_ngt[1], ng1); atomicMin(&sh_kmin[1], km1); }
  }
  __syncthreads();

  {  // pass 2: membership / stable-32nd / eq-list
    const int n0 = sh_ngt[0], n1 = sh_ngt[1];
    const unsigned int K320 = (n0 == 32) ? sh_kmin[0] : K0;
    const unsigned int K321 = (n1 == 32) ? sh_kmin[1] : K1;
#pragma unroll
    for (int q = 0; q < 16; ++q) {
      unsigned int k0 = kys[2 * q], k1 = kys[2 * q + 1];
      int gi = (q << 8) + t;
      if (k0 > K0) { int p = atomicAdd(&sh_cnt[0], 1); sh_list[0][p] = gi; }
      if (n0 == 32 && k0 == K320) atomicMax(&sh_mx[0], gi);
      if (n0 < 32 && k0 == K0) { int p = atomicAdd(&sh_ecnt[0], 1); if (p < 96) sh_eq[0][p] = gi; }
      if (k1 > K1) { int p = atomicAdd(&sh_cnt[1], 1); sh_list[1][p] = gi; }
      if (n1 == 32 && k1 == K321) atomicMax(&sh_mx[1], gi);
      if (n1 < 32 && k1 == K1) { int p = atomicAdd(&sh_ecnt[1], 1); if (p < 96) sh_eq[1][p] = gi; }
    }
  }
  __syncthreads();

  if (t < 2) {  // finalize per row (R12 verbatim)
    const int row = t, p = p0 + row;
    const int ngt = sh_ngt[row];
    const unsigned int K33v = sh_K33[row];
    if (ngt == 32) {
      const unsigned int K32v = sh_kmin[row];
      int target = sh_mx[row], pos = 31;
      for (int q2 = 0; q2 < 32; ++q2) if (sh_list[row][q2] == target) pos = q2;
      int tmp = sh_list[row][31]; sh_list[row][31] = sh_list[row][pos]; sh_list[row][pos] = tmp;
      gapb[p] = __float_as_uint(__fsub_rn(keyToFloat(K32v), keyToFloat(K33v)));
      i33out[p] = sh_i33[row];
    } else {
      int ec = sh_ecnt[row]; if (ec > 96) ec = 96;
      for (int a = 1; a < ec; ++a) {
        int v = sh_eq[row][a]; int bp = a - 1;
        while (bp >= 0 && sh_eq[row][bp] > v) { sh_eq[row][bp + 1] = sh_eq[row][bp]; --bp; }
        sh_eq[row][bp + 1] = v;
      }
      int need = 32 - ngt;
      for (int a = 0; a < need; ++a) sh_list[row][ngt + a] = sh_eq[row][a];
      gapb[p] = 0x7f800000u;
      i33out[p] = (need < ec) ? sh_eq[row][need] : -1;
    }
  }
  __syncthreads();
  if (t < 64) {
    int rr = t >> 5, k = t & 31;
    idxout[(size_t)(p0 + rr) * KNN + k] = sh_list[rr][k];
  }
}

// ---------------- K2f: flip the globally smallest-positive-gap row --------
__global__ __launch_bounds__(256) void k2f_flip(
    const unsigned int* __restrict__ gapb, const int* __restrict__ i33,
    int* __restrict__ idxout) {
  __shared__ unsigned int sk[256];
  __shared__ int sv[256];
  const int t = threadIdx.x;
  unsigned int best = 0xffffffffu;
  int brow = -1;
  for (int i = t; i < BB * NN; i += 256) {
    unsigned int g = gapb[i];
    if (g < best) { best = g; brow = i; }
  }
  sk[t] = best; sv[t] = brow;
  __syncthreads();
  for (int s = 128; s > 0; s >>= 1) {
    if (t < s && sk[t + s] < sk[t]) { sk[t] = sk[t + s]; sv[t] = sv[t + s]; }
    __syncthreads();
  }
  if (t == 0 && sv[0] >= 0 && sk[0] > 0u && sk[0] < 0x7f800000u) {
    idxout[(size_t)sv[0] * KNN + 31] = i33[sv[0]];
  }
}

// ---------------- K3: gather h=base+P[idx], k-max/min + BN partials -------
__global__ __launch_bounds__(256) void k3_gather_stats(
    const float* __restrict__ Pm, const float* __restrict__ basem,
    const int* __restrict__ idxb, float* __restrict__ hmax,
    float* __restrict__ hmin, float* __restrict__ statsP) {
  const int t = threadIdx.x, blk = blockIdx.x;
  const int w = t >> 6, o = t & 63;
  float s1 = 0.f, s2 = 0.f;
#pragma unroll
  for (int q = 0; q < 4; ++q) {
    int p = blk * 16 + w * 4 + q;
    int b = p >> 12;
    const float* Pb = Pm + (size_t)b * NN * OO;
    float bse = basem[(size_t)p * OO + o];
    const int* ix = idxb + (size_t)p * KNN;
    float mx = -INFINITY, mn = INFINITY;
#pragma unroll 8
    for (int k = 0; k < KNN; ++k) {
      int i = ix[k];
      float h = bse + Pb[(size_t)i * OO + o];
      mx = fmaxf(mx, h);
      mn = fminf(mn, h);
      s1 += h;
      s2 = fmaf(h, h, s2);
    }
    hmax[(size_t)p * OO + o] = mx;
    hmin[(size_t)p * OO + o] = mn;
  }
  __shared__ float red[512];
  red[t] = s1; red[256 + t] = s2;
  __syncthreads();
  if (t < 64) {
    statsP[blk * 128 + t]      = red[t] + red[64 + t] + red[128 + t] + red[192 + t];
    statsP[blk * 128 + 64 + t] = red[256 + t] + red[320 + t] + red[384 + t] + red[448 + t];
  }
}

// ---------------- K4: finalize BN scale/shift -----------------------------
__global__ __launch_bounds__(64) void k4_finalize(
    const float* __restrict__ statsP, const float* __restrict__ gamma,
    const float* __restrict__ beta, float* __restrict__ scsh) {
  const int o = threadIdx.x;
  float s1 = 0.f, s2 = 0.f;
  for (int i = 0; i < 1024; ++i) {
    s1 += statsP[i * 128 + o];
    s2 += statsP[i * 128 + 64 + o];
  }
  const float inv = 1.0f / 524288.0f;
  float mean = s1 * inv;
  float var = s2 * inv - mean * mean;
  float r = rsqrtf(var + 1e-5f);
  float sc = gamma[o] * r;
  scsh[o] = sc;
  scsh[64 + o] = beta[o] - mean * sc;
}

// ---------------- K5: epilogue: affine+relu on k-max/min, (B,O,N) --------
__global__ __launch_bounds__(256) void k5_epilogue(
    const float* __restrict__ hmax, const float* __restrict__ hmin,
    const float* __restrict__ scsh, float* __restrict__ out) {
  const int id = blockIdx.x * 256 + threadIdx.x;
  const int n = id & 4095, o = (id >> 12) & 63, b = id >> 18;
  float sc = scsh[o], sh = scsh[64 + o];
  size_t hoff = (((size_t)b << 12) + n) * OO + o;
  float H = (sc >= 0.f) ? hmax[hoff] : hmin[hoff];
  float y = sc * H + sh;
  out[id] = y > 0.f ? y : 0.f;
}

extern "C" void kernel_launch(void* const* d_in, const int* in_sizes, int n_in,
                              void* d_out, int out_size, void* d_ws, size_t ws_size,
                              hipStream_t stream) {
  const float* pts   = (const float*)d_in[0];
  const float* W     = (const float*)d_in[1];
  const float* gamma = (const float*)d_in[2];
  const float* beta  = (const float*)d_in[3];
  float* outp = (float*)d_out;
  float* wsf = (float*)d_ws;

  float*        xT    = wsf + XT_OFF;
  float*        sqf   = wsf + SQ_OFF;
  float*        P     = wsf + P_OFF;
  float*        base  = wsf + BASE_OFF;
  float*        hmax  = wsf + HMAX_OFF;
  float*        hmin  = wsf + HMIN_OFF;
  float*        stats = wsf + STATS_OFF;
  float*        scsh  = wsf + SCSH_OFF;
  int*          idx   = (int*)(wsf + IDX_OFF);
  unsigned int* gapb  = (unsigned int*)(wsf + GAP_OFF);
  int*          i33   = (int*)(wsf + I33_OFF);

  k1_transpose_sq<<<256, 256, 0, stream>>>(pts, xT, sqf);
  k2b_small_gemm<<<256, 256, 0, stream>>>(xT, W, P, base);
  k2_gram_select<<<8192, 256, 0, stream>>>(xT, sqf, idx, gapb, i33);
  k2f_flip<<<1, 256, 0, stream>>>(gapb, i33, idx);
  k3_gather_stats<<<1024, 256, 0, stream>>>(P, base, idx, hmax, hmin, stats);
  k4_finalize<<<1, 64, 0, stream>>>(stats, gamma, beta, scsh);
  k5_epilogue<<<4096, 256, 0, stream>>>(hmax, hmin, scsh, outp);
}